// Round 7
// baseline (207.648 us; speedup 1.0000x reference)
//
#include <hip/hip_runtime.h>

#define HDIM 128
#define XDIM 66
#define EDIM 6
#define NGRAPHS 256
#define LN_EPS 1e-5f

#define HBINS 25600          // bins per range (100 KB LDS)
#define HR 4                 // index ranges: covers HR*HBINS = 102400 >= N
#define HB 16                // edge slices per (range, array)
#define CBINS (HR * HBINS)   // c_src / c_dst allocation size
#define NBX 1024             // k_xsum grid

#define T0R 64               // k_upd0 tile rows
#define T0PAD 532            // 66*8 + 4 : bank phase 20 -> 2-way max

// ---------------- K1a: partial LDS histograms ----------------
__global__ __launch_bounds__(256) void k_hist_part(const int* __restrict__ ei,
        float* __restrict__ part, int E) {
    __shared__ float lh[HBINS];
    int b = blockIdx.x;
    int s = b & (HB - 1);
    int r = (b / HB) & (HR - 1);
    int a = b / (HB * HR);
    int t = threadIdx.x;
    for (int i = t; i < HBINS; i += 256) lh[i] = 0.f;
    __syncthreads();
    const int* src = ei + (size_t)a * E;
    int chunk = (((E + HB - 1) / HB) + 3) & ~3;
    int lo = s * chunk;
    int hi = min(E, lo + chunk);
    int base = r * HBINS;
    if ((E & 3) == 0) {
        for (int i = lo + t * 4; i < hi; i += 256 * 4) {
            if (i + 4 <= hi) {
                int4 v = *(const int4*)(src + i);
                unsigned u0 = (unsigned)(v.x - base);
                unsigned u1 = (unsigned)(v.y - base);
                unsigned u2 = (unsigned)(v.z - base);
                unsigned u3 = (unsigned)(v.w - base);
                if (u0 < HBINS) atomicAdd(&lh[u0], 1.0f);
                if (u1 < HBINS) atomicAdd(&lh[u1], 1.0f);
                if (u2 < HBINS) atomicAdd(&lh[u2], 1.0f);
                if (u3 < HBINS) atomicAdd(&lh[u3], 1.0f);
            } else {
                for (int j = i; j < hi; ++j) {
                    unsigned u = (unsigned)(src[j] - base);
                    if (u < HBINS) atomicAdd(&lh[u], 1.0f);
                }
            }
        }
    } else {
        for (int i = lo + t; i < hi; i += 256) {
            unsigned u = (unsigned)(src[i] - base);
            if (u < HBINS) atomicAdd(&lh[u], 1.0f);
        }
    }
    __syncthreads();
    float* dst = part + (size_t)b * HBINS;
    for (int i = t; i < HBINS / 4; i += 256)
        ((float4*)dst)[i] = ((const float4*)lh)[i];
}

// ---------------- K1b: reduce slices -> c_src, c_dst ----------------
__global__ __launch_bounds__(256) void k_hist_red(const float* __restrict__ part,
        float* __restrict__ c_src, float* __restrict__ c_dst) {
    int n = blockIdx.x * 256 + threadIdx.x;
    if (n >= CBINS) return;
    int r = n / HBINS, off = n - r * HBINS;
    const float* p0 = part + ((size_t)(0 * HR + r) * HB) * HBINS + off;
    const float* p1 = part + ((size_t)(1 * HR + r) * HB) * HBINS + off;
    float s0 = 0.f, s1 = 0.f;
#pragma unroll 8
    for (int s = 0; s < HB; ++s) {
        s0 += p0[(size_t)s * HBINS];
        s1 += p1[(size_t)s * HBINS];
    }
    c_src[n] = s0;
    c_dst[n] = s1;
}

// ---------------- K2: column-sum of edge_attr (E,6) ----------------
__global__ __launch_bounds__(256) void k_edgesum(const float* __restrict__ ea,
                                                 float* __restrict__ sum_attr, int E) {
    int nchunk = E >> 1;
    float a0 = 0, a1 = 0, a2 = 0, a3 = 0, a4 = 0, a5 = 0;
    for (int c = blockIdx.x * blockDim.x + threadIdx.x; c < nchunk;
         c += gridDim.x * blockDim.x) {
        const float4* p = (const float4*)(ea + (size_t)c * 12);
        float4 v0 = p[0], v1 = p[1], v2 = p[2];
        a0 += v0.x + v1.z;  a1 += v0.y + v1.w;  a2 += v0.z + v2.x;
        a3 += v0.w + v2.y;  a4 += v1.x + v2.z;  a5 += v1.y + v2.w;
    }
#pragma unroll
    for (int m = 32; m; m >>= 1) {
        a0 += __shfl_xor(a0, m); a1 += __shfl_xor(a1, m); a2 += __shfl_xor(a2, m);
        a3 += __shfl_xor(a3, m); a4 += __shfl_xor(a4, m); a5 += __shfl_xor(a5, m);
    }
    __shared__ float sbuf[4][6];
    int lane = threadIdx.x & 63, w = threadIdx.x >> 6;
    if (lane == 0) {
        sbuf[w][0] = a0; sbuf[w][1] = a1; sbuf[w][2] = a2;
        sbuf[w][3] = a3; sbuf[w][4] = a4; sbuf[w][5] = a5;
    }
    __syncthreads();
    if (threadIdx.x < 6) {
        float s = sbuf[0][threadIdx.x] + sbuf[1][threadIdx.x] +
                  sbuf[2][threadIdx.x] + sbuf[3][threadIdx.x];
        atomicAdd(&sum_attr[threadIdx.x], s);
    }
    if (blockIdx.x == 0 && threadIdx.x < 6 && (E & 1))
        atomicAdd(&sum_attr[threadIdx.x], ea[(size_t)(E - 1) * 6 + threadIdx.x]);
}

// ---------------- K3: weighted column sums of x -> per-block partials ----------------
__global__ __launch_bounds__(256) void k_xsum(const float* __restrict__ x,
        const float* __restrict__ c_src, const float* __restrict__ c_dst,
        float* __restrict__ xpart, int N) {
    int lane = threadIdx.x & 63, w = threadIdx.x >> 6;
    int wid = blockIdx.x * 4 + w, nw = gridDim.x * 4;
    float as0 = 0, ad0 = 0, as1 = 0, ad1 = 0;
    int Q = N >> 2;
    for (int q = wid; q < Q; q += nw) {
        int n = q * 4;
        const float* xr = x + (size_t)n * XDIM;
        float x0 = xr[lane];
        float x1 = xr[XDIM + lane];
        float x2 = xr[2 * XDIM + lane];
        float x3 = xr[3 * XDIM + lane];
        float4 cs = *(const float4*)(c_src + n);
        float4 cd = *(const float4*)(c_dst + n);
        as0 = fmaf(cs.x, x0, as0); as0 = fmaf(cs.y, x1, as0);
        as0 = fmaf(cs.z, x2, as0); as0 = fmaf(cs.w, x3, as0);
        ad0 = fmaf(cd.x, x0, ad0); ad0 = fmaf(cd.y, x1, ad0);
        ad0 = fmaf(cd.z, x2, ad0); ad0 = fmaf(cd.w, x3, ad0);
        if (lane < 2) {
            float e0 = xr[64 + lane];
            float e1 = xr[XDIM + 64 + lane];
            float e2 = xr[2 * XDIM + 64 + lane];
            float e3 = xr[3 * XDIM + 64 + lane];
            as1 = fmaf(cs.x, e0, as1); as1 = fmaf(cs.y, e1, as1);
            as1 = fmaf(cs.z, e2, as1); as1 = fmaf(cs.w, e3, as1);
            ad1 = fmaf(cd.x, e0, ad1); ad1 = fmaf(cd.y, e1, ad1);
            ad1 = fmaf(cd.z, e2, ad1); ad1 = fmaf(cd.w, e3, ad1);
        }
    }
    if (wid == 0) {
        for (int n = Q * 4; n < N; ++n) {
            const float* xr = x + (size_t)n * XDIM;
            float cs = c_src[n], cd = c_dst[n];
            float xv = xr[lane];
            as0 = fmaf(cs, xv, as0);
            ad0 = fmaf(cd, xv, ad0);
            if (lane < 2) {
                float xe = xr[64 + lane];
                as1 = fmaf(cs, xe, as1);
                ad1 = fmaf(cd, xe, ad1);
            }
        }
    }
    __shared__ float redS[4][XDIM], redD[4][XDIM];
    redS[w][lane] = as0;  redD[w][lane] = ad0;
    if (lane < 2) { redS[w][64 + lane] = as1;  redD[w][64 + lane] = ad1; }
    __syncthreads();
    int t = threadIdx.x;
    float* xp = xpart + (size_t)blockIdx.x * 136;
    if (t < XDIM) {
        xp[t]        = redS[0][t] + redS[1][t] + redS[2][t] + redS[3][t];
        xp[XDIM + t] = redD[0][t] + redD[1][t] + redD[2][t] + redD[3][t];
    }
}

// ---------------- K3b: reduce xpart rows -> xs[132] ----------------
__global__ __launch_bounds__(64) void k_xred(const float* __restrict__ xpart,
                                             float* __restrict__ xs, int nb) {
    int e = blockIdx.x;
    int lane = threadIdx.x;
    float s = 0.f;
    for (int b = lane; b < nb; b += 64)
        s += xpart[(size_t)b * 136 + e];
#pragma unroll
    for (int m = 32; m; m >>= 1) s += __shfl_xor(s, m);
    if (lane == 0) xs[e] = s;
}

// ---------------- K6: mean_msg = ([s_src,s_dst,se] @ W)/E + mp_b ----------------
template <int FIRST>
__global__ __launch_bounds__(256) void k_mm(const float* __restrict__ sv,
        const float* __restrict__ sum_attr, const float* __restrict__ w_edge,
        const float* __restrict__ b_edge, const float* __restrict__ W,
        const float* __restrict__ mpb, float* __restrict__ mean_msg, float Ef,
        const float* __restrict__ w_node, const float* __restrict__ b_node) {
    __shared__ float sc[384];
    __shared__ float mred[256];
    int t = threadIdx.x;
    if (t < 128) {
        float ssrc, sdst;
        if (FIRST) {
            ssrc = Ef * b_node[t];
            sdst = ssrc;
#pragma unroll
            for (int k = 0; k < XDIM; ++k) {
                float wv = w_node[k * HDIM + t];
                ssrc = fmaf(sv[k], wv, ssrc);
                sdst = fmaf(sv[XDIM + k], wv, sdst);
            }
        } else {
            ssrc = sv[t] + sv[t + 128];
            sdst = sv[256 + t] + sv[384 + t];
        }
        sc[t] = ssrc;
        sc[128 + t] = sdst;
        float se = Ef * b_edge[t];
#pragma unroll
        for (int k = 0; k < EDIM; ++k) se = fmaf(sum_attr[k], w_edge[k * HDIM + t], se);
        sc[256 + t] = se;
    }
    __syncthreads();
    int col = blockIdx.x * 16 + (t & 15);
    int rg = t >> 4;
    float acc = 0.f;
#pragma unroll 4
    for (int r = rg * 24; r < rg * 24 + 24; ++r)
        acc = fmaf(sc[r], W[r * HDIM + col], acc);
    mred[t] = acc;
    __syncthreads();
    if (t < 16) {
        float s = 0.f;
#pragma unroll
        for (int g = 0; g < 16; ++g) s += mred[g * 16 + t];
        mean_msg[blockIdx.x * 16 + t] = s / Ef + mpb[blockIdx.x * 16 + t];
    }
}

// ---------------- K5: reduce per-block partials -> sbuf[512] ----------------
__global__ __launch_bounds__(256) void k_red(const float* __restrict__ partials,
                                             float* __restrict__ sbuf, int nb) {
    int b0 = blockIdx.x * 32;
    int b1 = min(nb, b0 + 32);
    int t = threadIdx.x;
    float s0 = 0.f, s1 = 0.f;
    for (int b = b0; b < b1; ++b) {
        const float* row = partials + (size_t)b * 512;
        s0 += row[t];
        s1 += row[t + 256];
    }
    atomicAdd(&sbuf[t], s0);
    atomicAdd(&sbuf[t + 256], s1);
}

// ---------------- K7: fused layer-0, 8x8 register blocking, phased-LDS ----------------
// thread t: cg = t&15 (cols cg*8..+8), rg = t>>4 (rows rg*8..+8). 64-row tile.
__global__ __launch_bounds__(128) void k_upd0(
        const float* __restrict__ x, const float* __restrict__ w_node,
        const float* __restrict__ b_node, const float* __restrict__ mean_msg,
        const float* __restrict__ ln_g, const float* __restrict__ ln_b,
        const float* __restrict__ c_src, const float* __restrict__ c_dst,
        float* __restrict__ h, float* __restrict__ partials, int N) {
    __shared__ float wl[16 * T0PAD];   // wl[cg][k*8+j] = w_node[k][cg*8+j]
    __shared__ float xt[8 * T0PAD];    // xt[rg][k*8+j] = x[rowbase+rg*8+j][k]
    int t = threadIdx.x;
    int cg = t & 15, rg = t >> 4;
    // stage W (8448 elems, 66/thread, coalesced reads)
    for (int i = t; i < XDIM * HDIM; i += 128) {
        int k = i >> 7, c = i & 127;
        wl[(c >> 3) * T0PAD + k * 8 + (c & 7)] = w_node[i];
    }
    // stage x tile transposed (4224 elems, 33/thread)
    int rowbase = blockIdx.x * T0R;
    const float* xg = x + (size_t)rowbase * XDIM;
    int lim = (min(T0R, N - rowbase)) * XDIM;
    for (int i = t; i < T0R * XDIM; i += 128) {
        float v = (i < lim) ? xg[i] : 0.f;
        int r = i / XDIM, k = i - r * XDIM;
        xt[(r >> 3) * T0PAD + k * 8 + (r & 7)] = v;
    }
    int c0 = cg * 8;
    float4 b4a = *(const float4*)(b_node + c0);
    float4 b4b = *(const float4*)(b_node + c0 + 4);
    float4 m4a = *(const float4*)(mean_msg + c0);
    float4 m4b = *(const float4*)(mean_msg + c0 + 4);
    float4 bma = {b4a.x + m4a.x, b4a.y + m4a.y, b4a.z + m4a.z, b4a.w + m4a.w};
    float4 bmb = {b4b.x + m4b.x, b4b.y + m4b.y, b4b.z + m4b.z, b4b.w + m4b.w};
    float4 ga  = *(const float4*)(ln_g + c0);
    float4 gb  = *(const float4*)(ln_g + c0 + 4);
    float4 lba = *(const float4*)(ln_b + c0);
    float4 lbb = *(const float4*)(ln_b + c0 + 4);
    __syncthreads();

    float4 acc[8][2];
#pragma unroll
    for (int r = 0; r < 8; ++r) { acc[r][0] = bma; acc[r][1] = bmb; }
    const float* xp = xt + rg * T0PAD;
    const float* wp = wl + cg * T0PAD;
#pragma unroll 2
    for (int k = 0; k < XDIM; ++k) {
        float4 xa = *(const float4*)(xp + k * 8);
        float4 xb = *(const float4*)(xp + k * 8 + 4);
        float4 wa = *(const float4*)(wp + k * 8);
        float4 wb = *(const float4*)(wp + k * 8 + 4);
        float xr[8] = {xa.x, xa.y, xa.z, xa.w, xb.x, xb.y, xb.z, xb.w};
#pragma unroll
        for (int r = 0; r < 8; ++r) {
            acc[r][0].x = fmaf(xr[r], wa.x, acc[r][0].x);
            acc[r][0].y = fmaf(xr[r], wa.y, acc[r][0].y);
            acc[r][0].z = fmaf(xr[r], wa.z, acc[r][0].z);
            acc[r][0].w = fmaf(xr[r], wa.w, acc[r][0].w);
            acc[r][1].x = fmaf(xr[r], wb.x, acc[r][1].x);
            acc[r][1].y = fmaf(xr[r], wb.y, acc[r][1].y);
            acc[r][1].z = fmaf(xr[r], wb.z, acc[r][1].z);
            acc[r][1].w = fmaf(xr[r], wb.w, acc[r][1].w);
        }
    }
    // epilogue: LN+relu per row (reduce across 16 cgs), store, weighted sums
    int rbase = rowbase + rg * 8;
    float4 csA = *(const float4*)(c_src + rbase);
    float4 csB = *(const float4*)(c_src + rbase + 4);
    float4 cdA = *(const float4*)(c_dst + rbase);
    float4 cdB = *(const float4*)(c_dst + rbase + 4);
    float csArr[8] = {csA.x, csA.y, csA.z, csA.w, csB.x, csB.y, csB.z, csB.w};
    float cdArr[8] = {cdA.x, cdA.y, cdA.z, cdA.w, cdB.x, cdB.y, cdB.z, cdB.w};
    float4 accS0 = {0,0,0,0}, accS1 = {0,0,0,0}, accD0 = {0,0,0,0}, accD1 = {0,0,0,0};
#pragma unroll
    for (int r = 0; r < 8; ++r) {
        float4 a0 = acc[r][0], a1 = acc[r][1];
        float s = a0.x + a0.y + a0.z + a0.w + a1.x + a1.y + a1.z + a1.w;
#pragma unroll
        for (int m = 8; m; m >>= 1) s += __shfl_xor(s, m);   // 16-lane cg group
        float mu = s * (1.0f / HDIM);
        float d0 = a0.x - mu, d1 = a0.y - mu, d2 = a0.z - mu, d3 = a0.w - mu;
        float d4 = a1.x - mu, d5 = a1.y - mu, d6 = a1.z - mu, d7 = a1.w - mu;
        float q = d0*d0 + d1*d1 + d2*d2 + d3*d3 + d4*d4 + d5*d5 + d6*d6 + d7*d7;
#pragma unroll
        for (int m = 8; m; m >>= 1) q += __shfl_xor(q, m);
        float rs = rsqrtf(q * (1.0f / HDIM) + LN_EPS);
        float4 o0, o1;
        o0.x = fmaxf(0.f, fmaf(d0 * rs, ga.x, lba.x));
        o0.y = fmaxf(0.f, fmaf(d1 * rs, ga.y, lba.y));
        o0.z = fmaxf(0.f, fmaf(d2 * rs, ga.z, lba.z));
        o0.w = fmaxf(0.f, fmaf(d3 * rs, ga.w, lba.w));
        o1.x = fmaxf(0.f, fmaf(d4 * rs, gb.x, lbb.x));
        o1.y = fmaxf(0.f, fmaf(d5 * rs, gb.y, lbb.y));
        o1.z = fmaxf(0.f, fmaf(d6 * rs, gb.z, lbb.z));
        o1.w = fmaxf(0.f, fmaf(d7 * rs, gb.w, lbb.w));
        int row = rbase + r;
        if (row < N) {
            *(float4*)(h + (size_t)row * HDIM + c0) = o0;
            *(float4*)(h + (size_t)row * HDIM + c0 + 4) = o1;
        }
        float cs = csArr[r], cd = cdArr[r];
        accS0.x = fmaf(cs, o0.x, accS0.x); accS0.y = fmaf(cs, o0.y, accS0.y);
        accS0.z = fmaf(cs, o0.z, accS0.z); accS0.w = fmaf(cs, o0.w, accS0.w);
        accS1.x = fmaf(cs, o1.x, accS1.x); accS1.y = fmaf(cs, o1.y, accS1.y);
        accS1.z = fmaf(cs, o1.z, accS1.z); accS1.w = fmaf(cs, o1.w, accS1.w);
        accD0.x = fmaf(cd, o0.x, accD0.x); accD0.y = fmaf(cd, o0.y, accD0.y);
        accD0.z = fmaf(cd, o0.z, accD0.z); accD0.w = fmaf(cd, o0.w, accD0.w);
        accD1.x = fmaf(cd, o1.x, accD1.x); accD1.y = fmaf(cd, o1.y, accD1.y);
        accD1.z = fmaf(cd, o1.z, accD1.z); accD1.w = fmaf(cd, o1.w, accD1.w);
    }
    // block reduce across 8 rgs (reuse xt: need 2048 floats <= 4256)
    __syncthreads();
    float* redS = xt;
    float* redD = xt + 1024;
    *(float4*)(redS + rg * HDIM + c0)     = accS0;
    *(float4*)(redS + rg * HDIM + c0 + 4) = accS1;
    *(float4*)(redD + rg * HDIM + c0)     = accD0;
    *(float4*)(redD + rg * HDIM + c0 + 4) = accD1;
    __syncthreads();
    float s = 0.f, d = 0.f;
#pragma unroll
    for (int gi = 0; gi < 8; ++gi) {
        s += redS[gi * HDIM + t];
        d += redD[gi * HDIM + t];
    }
    float* row = partials + (size_t)blockIdx.x * 512;
    row[t] = s;        row[t + 128] = 0.f;
    row[t + 256] = d;  row[t + 384] = 0.f;
}

// ---------------- LN helper ----------------
__device__ __forceinline__ float2 ln_relu2(float2 v, float2 g, float2 bb) {
    float s = v.x + v.y;
#pragma unroll
    for (int m = 32; m; m >>= 1) s += __shfl_xor(s, m);
    float mu = s * (1.0f / HDIM);
    float dx = v.x - mu, dy = v.y - mu;
    float q = dx * dx + dy * dy;
#pragma unroll
    for (int m = 32; m; m >>= 1) q += __shfl_xor(q, m);
    float rs = rsqrtf(q * (1.0f / HDIM) + LN_EPS);
    float2 o;
    o.x = fmaxf(0.f, fmaf(dx * rs, g.x, bb.x));
    o.y = fmaxf(0.f, fmaf(dy * rs, g.y, bb.y));
    return o;
}

// ---------------- K8: h = relu(LN(h + mm)); next-layer sums or pooling ----------------
template <int LAST>
__global__ __launch_bounds__(256) void k_update(
        float* __restrict__ h, const float* __restrict__ mean_msg,
        const float* __restrict__ ln_g, const float* __restrict__ ln_b,
        const float* __restrict__ c_src, const float* __restrict__ c_dst,
        const int* __restrict__ batch, float* __restrict__ partials,
        float* __restrict__ pooled, int N, int cpb) {
    int t = threadIdx.x;
    int lane = t & 63, w = t >> 6;
    int c0 = lane * 2;
    float2 mm = *(const float2*)(mean_msg + c0);
    float2 g  = *(const float2*)(ln_g + c0);
    float2 bb = *(const float2*)(ln_b + c0);
    int start = blockIdx.x * cpb;
    int end = min(N, start + cpb);
    int spw = (cpb + 3) >> 2;
    int ns = start + w * spw;
    int ne = min(end, ns + spw);
    float2 accS = {0.f, 0.f}, accD = {0.f, 0.f}, accP = {0.f, 0.f};
    int cur_g = -1;
    int n = ns;
    for (; n + 4 <= ne; n += 4) {
        float2 v0 = *(const float2*)(h + (size_t)(n    ) * HDIM + c0);
        float2 v1 = *(const float2*)(h + (size_t)(n + 1) * HDIM + c0);
        float2 v2 = *(const float2*)(h + (size_t)(n + 2) * HDIM + c0);
        float2 v3 = *(const float2*)(h + (size_t)(n + 3) * HDIM + c0);
        v0.x += mm.x; v0.y += mm.y;  v1.x += mm.x; v1.y += mm.y;
        v2.x += mm.x; v2.y += mm.y;  v3.x += mm.x; v3.y += mm.y;
        float2 o0 = ln_relu2(v0, g, bb);
        float2 o1 = ln_relu2(v1, g, bb);
        float2 o2 = ln_relu2(v2, g, bb);
        float2 o3 = ln_relu2(v3, g, bb);
        if (LAST) {
            int gi[4] = {batch[n], batch[n + 1], batch[n + 2], batch[n + 3]};
            float2 oo[4] = {o0, o1, o2, o3};
#pragma unroll
            for (int r = 0; r < 4; ++r) {
                if (gi[r] != cur_g) {
                    if (cur_g >= 0) {
                        atomicAdd(&pooled[cur_g * HDIM + c0],     accP.x);
                        atomicAdd(&pooled[cur_g * HDIM + c0 + 1], accP.y);
                    }
                    accP.x = 0.f; accP.y = 0.f;
                    cur_g = gi[r];
                }
                accP.x += oo[r].x; accP.y += oo[r].y;
            }
        } else {
            *(float2*)(h + (size_t)(n    ) * HDIM + c0) = o0;
            *(float2*)(h + (size_t)(n + 1) * HDIM + c0) = o1;
            *(float2*)(h + (size_t)(n + 2) * HDIM + c0) = o2;
            *(float2*)(h + (size_t)(n + 3) * HDIM + c0) = o3;
            float cs0 = c_src[n], cs1 = c_src[n+1], cs2 = c_src[n+2], cs3 = c_src[n+3];
            float cd0 = c_dst[n], cd1 = c_dst[n+1], cd2 = c_dst[n+2], cd3 = c_dst[n+3];
            accS.x = fmaf(cs0, o0.x, accS.x); accS.y = fmaf(cs0, o0.y, accS.y);
            accS.x = fmaf(cs1, o1.x, accS.x); accS.y = fmaf(cs1, o1.y, accS.y);
            accS.x = fmaf(cs2, o2.x, accS.x); accS.y = fmaf(cs2, o2.y, accS.y);
            accS.x = fmaf(cs3, o3.x, accS.x); accS.y = fmaf(cs3, o3.y, accS.y);
            accD.x = fmaf(cd0, o0.x, accD.x); accD.y = fmaf(cd0, o0.y, accD.y);
            accD.x = fmaf(cd1, o1.x, accD.x); accD.y = fmaf(cd1, o1.y, accD.y);
            accD.x = fmaf(cd2, o2.x, accD.x); accD.y = fmaf(cd2, o2.y, accD.y);
            accD.x = fmaf(cd3, o3.x, accD.x); accD.y = fmaf(cd3, o3.y, accD.y);
        }
    }
    for (; n < ne; ++n) {
        float2 v = *(const float2*)(h + (size_t)n * HDIM + c0);
        v.x += mm.x; v.y += mm.y;
        float2 o = ln_relu2(v, g, bb);
        if (LAST) {
            int gg = batch[n];
            if (gg != cur_g) {
                if (cur_g >= 0) {
                    atomicAdd(&pooled[cur_g * HDIM + c0],     accP.x);
                    atomicAdd(&pooled[cur_g * HDIM + c0 + 1], accP.y);
                }
                accP.x = 0.f; accP.y = 0.f;
                cur_g = gg;
            }
            accP.x += o.x; accP.y += o.y;
        } else {
            *(float2*)(h + (size_t)n * HDIM + c0) = o;
            float cs = c_src[n], cd = c_dst[n];
            accS.x = fmaf(cs, o.x, accS.x); accS.y = fmaf(cs, o.y, accS.y);
            accD.x = fmaf(cd, o.x, accD.x); accD.y = fmaf(cd, o.y, accD.y);
        }
    }
    if (LAST) {
        if (cur_g >= 0) {
            atomicAdd(&pooled[cur_g * HDIM + c0],     accP.x);
            atomicAdd(&pooled[cur_g * HDIM + c0 + 1], accP.y);
        }
    } else {
        __shared__ float sb[HDIM], db[HDIM];
        if (t < HDIM) { sb[t] = 0.f; db[t] = 0.f; }
        __syncthreads();
        atomicAdd(&sb[c0], accS.x); atomicAdd(&sb[c0 + 1], accS.y);
        atomicAdd(&db[c0], accD.x); atomicAdd(&db[c0 + 1], accD.y);
        __syncthreads();
        float* row = partials + (size_t)blockIdx.x * 512;
        if (t < 128) {
            row[t] = sb[t];        row[t + 128] = 0.f;
            row[t + 256] = db[t];  row[t + 384] = 0.f;
        }
    }
}

// ---------------- K9: out = (pooled / max(cnt,1)) @ w_out + b_out ----------------
__global__ __launch_bounds__(128) void k_out(const float* __restrict__ pooled,
        const int* __restrict__ batch, const float* __restrict__ w_out,
        const float* __restrict__ b_out, float* __restrict__ out, int N) {
    int gph = blockIdx.x;
    int t = threadIdx.x;
    __shared__ float p[HDIM];
    __shared__ int cntS;
    if (t == 0) {
        int lo = 0, hi = N;
        while (lo < hi) { int mid = (lo + hi) >> 1; if (batch[mid] < gph) lo = mid + 1; else hi = mid; }
        int lo2 = lo, hi2 = N;
        while (lo2 < hi2) { int mid = (lo2 + hi2) >> 1; if (batch[mid] <= gph) lo2 = mid + 1; else hi2 = mid; }
        cntS = lo2 - lo;
    }
    __syncthreads();
    float inv = 1.0f / fmaxf((float)cntS, 1.0f);
    p[t] = pooled[gph * HDIM + t] * inv;
    __syncthreads();
    float acc = b_out[t];
#pragma unroll 8
    for (int k = 0; k < HDIM; ++k) acc = fmaf(p[k], w_out[k * HDIM + t], acc);
    out[gph * HDIM + t] = acc;
}

extern "C" void kernel_launch(void* const* d_in, const int* in_sizes, int n_in,
                              void* d_out, int out_size, void* d_ws, size_t ws_size,
                              hipStream_t stream) {
    const float* x      = (const float*)d_in[0];
    const int*   ei     = (const int*)d_in[1];
    const float* ea     = (const float*)d_in[2];
    const int*   batch  = (const int*)d_in[3];
    const float* w_node = (const float*)d_in[4];
    const float* b_node = (const float*)d_in[5];
    const float* w_edge = (const float*)d_in[6];
    const float* b_edge = (const float*)d_in[7];
    const float* mp_w   = (const float*)d_in[8];
    const float* mp_b   = (const float*)d_in[9];
    const float* ln_g   = (const float*)d_in[10];
    const float* ln_b   = (const float*)d_in[11];
    const float* w_out  = (const float*)d_in[12];
    const float* b_out  = (const float*)d_in[13];
    float* out = (float*)d_out;
    int N = in_sizes[3];
    int E = in_sizes[2] / EDIM;
    float Ef = (float)E;
    int ntiles0 = (N + T0R - 1) / T0R;

    float* ws = (float*)d_ws;
    size_t off = 0;
    float* h        = ws + off; off += (size_t)N * HDIM;       // hist partials overlay here
    float* hist_part = h;   // 2*HR*HB*HBINS*4B = 13.1MB <= 51.2MB
    float* partials = ws + off; off += (size_t)2048 * 512;
    float* mean_msg = ws + off; off += 128;
    float* c_src    = ws + off; off += CBINS;
    float* c_dst    = ws + off; off += CBINS;
    float* xpart    = ws + off; off += (size_t)NBX * 136;
    float* xs       = ws + off; off += 136;
    // ---- accumulator region (contiguous, zeroed every call) ----
    float* acc0     = ws + off;
    float* sum_attr = ws + off; off += 8;
    float* sbuf1    = ws + off; off += 512;
    float* sbuf2    = ws + off; off += 512;
    float* pooled   = ws + off; off += NGRAPHS * HDIM;
    size_t zero_count = (size_t)(ws + off - acc0);
    hipMemsetAsync(acc0, 0, zero_count * sizeof(float), stream);

    k_hist_part<<<2 * HR * HB, 256, 0, stream>>>(ei, hist_part, E);
    k_hist_red<<<(CBINS + 255) / 256, 256, 0, stream>>>(hist_part, c_src, c_dst);
    k_edgesum<<<128, 256, 0, stream>>>(ea, sum_attr, E);
    k_xsum<<<NBX, 256, 0, stream>>>(x, c_src, c_dst, xpart, N);
    k_xred<<<2 * XDIM, 64, 0, stream>>>(xpart, xs, NBX);

    const int NB = 1024;
    int cpb = (N + NB - 1) / NB;

    // layer 0
    k_mm<1><<<8, 256, 0, stream>>>(xs, sum_attr, w_edge, b_edge,
                                   mp_w, mp_b, mean_msg, Ef, w_node, b_node);
    k_upd0<<<ntiles0, 128, 0, stream>>>(x, w_node, b_node, mean_msg, ln_g, ln_b,
                                        c_src, c_dst, h, partials, N);
    // layer 1
    k_red<<<(ntiles0 + 31) / 32, 256, 0, stream>>>(partials, sbuf1, ntiles0);
    k_mm<0><<<8, 256, 0, stream>>>(sbuf1, sum_attr, w_edge, b_edge,
                                   mp_w + (size_t)1 * 384 * HDIM,
                                   mp_b + (size_t)1 * HDIM, mean_msg, Ef,
                                   w_node, b_node);
    k_update<0><<<NB, 256, 0, stream>>>(h, mean_msg, ln_g, ln_b, c_src, c_dst,
                                        batch, partials, pooled, N, cpb);
    // layer 2
    k_red<<<NB / 32, 256, 0, stream>>>(partials, sbuf2, NB);
    k_mm<0><<<8, 256, 0, stream>>>(sbuf2, sum_attr, w_edge, b_edge,
                                   mp_w + (size_t)2 * 384 * HDIM,
                                   mp_b + (size_t)2 * HDIM, mean_msg, Ef,
                                   w_node, b_node);
    k_update<1><<<NB, 256, 0, stream>>>(h, mean_msg, ln_g, ln_b, c_src, c_dst,
                                        batch, partials, pooled, N, cpb);

    k_out<<<NGRAPHS, HDIM, 0, stream>>>(pooled, batch, w_out, b_out, out, N);
}

// Round 8
// 195.110 us; speedup vs baseline: 1.0643x; 1.0643x over previous
//
#include <hip/hip_runtime.h>

#define HDIM 128
#define XDIM 66
#define EDIM 6
#define NGRAPHS 256
#define LN_EPS 1e-5f

#define HBINS 25600          // bins per range (100 KB LDS)
#define HR 4                 // index ranges: covers HR*HBINS = 102400 >= N
#define HB 16                // edge slices per (range, array)
#define CBINS (HR * HBINS)
#define NBX 1024             // k_xsum grid

#define KP 104               // padded K for bf16 MFMA (66 -> 104, 208B rows)

typedef __attribute__((ext_vector_type(8))) short sv8;    // 8 bf16
typedef __attribute__((ext_vector_type(4))) float fv4;

__device__ __forceinline__ unsigned short f2bf(float f) {
    unsigned u = __float_as_uint(f);
    unsigned r = (u + 0x7FFFu + ((u >> 16) & 1u)) >> 16;
    return (unsigned short)r;
}

// ---------------- K0: one-time W^T bf16, K-padded ----------------
__global__ __launch_bounds__(128) void k_prep(const float* __restrict__ w_node,
                                              unsigned short* __restrict__ wtg) {
    int col = threadIdx.x;   // 128 threads
    for (int kp = 0; kp < KP; ++kp) {
        float v = (kp < XDIM) ? w_node[kp * HDIM + col] : 0.f;
        wtg[col * KP + kp] = f2bf(v);
    }
}

// ---------------- K1a: partial LDS histograms ----------------
__global__ __launch_bounds__(256) void k_hist_part(const int* __restrict__ ei,
        float* __restrict__ part, int E) {
    __shared__ float lh[HBINS];
    int b = blockIdx.x;
    int s = b & (HB - 1);
    int r = (b / HB) & (HR - 1);
    int a = b / (HB * HR);
    int t = threadIdx.x;
    for (int i = t; i < HBINS; i += 256) lh[i] = 0.f;
    __syncthreads();
    const int* src = ei + (size_t)a * E;
    int chunk = (((E + HB - 1) / HB) + 3) & ~3;
    int lo = s * chunk;
    int hi = min(E, lo + chunk);
    int base = r * HBINS;
    if ((E & 3) == 0) {
        for (int i = lo + t * 4; i < hi; i += 256 * 4) {
            if (i + 4 <= hi) {
                int4 v = *(const int4*)(src + i);
                unsigned u0 = (unsigned)(v.x - base);
                unsigned u1 = (unsigned)(v.y - base);
                unsigned u2 = (unsigned)(v.z - base);
                unsigned u3 = (unsigned)(v.w - base);
                if (u0 < HBINS) atomicAdd(&lh[u0], 1.0f);
                if (u1 < HBINS) atomicAdd(&lh[u1], 1.0f);
                if (u2 < HBINS) atomicAdd(&lh[u2], 1.0f);
                if (u3 < HBINS) atomicAdd(&lh[u3], 1.0f);
            } else {
                for (int j = i; j < hi; ++j) {
                    unsigned u = (unsigned)(src[j] - base);
                    if (u < HBINS) atomicAdd(&lh[u], 1.0f);
                }
            }
        }
    } else {
        for (int i = lo + t; i < hi; i += 256) {
            unsigned u = (unsigned)(src[i] - base);
            if (u < HBINS) atomicAdd(&lh[u], 1.0f);
        }
    }
    __syncthreads();
    float* dst = part + (size_t)b * HBINS;
    for (int i = t; i < HBINS / 4; i += 256)
        ((float4*)dst)[i] = ((const float4*)lh)[i];
}

// ---------------- K1b: reduce slices -> c_src, c_dst ----------------
__global__ __launch_bounds__(256) void k_hist_red(const float* __restrict__ part,
        float* __restrict__ c_src, float* __restrict__ c_dst) {
    int n = blockIdx.x * 256 + threadIdx.x;
    if (n >= CBINS) return;
    int r = n / HBINS, off = n - r * HBINS;
    const float* p0 = part + ((size_t)(0 * HR + r) * HB) * HBINS + off;
    const float* p1 = part + ((size_t)(1 * HR + r) * HB) * HBINS + off;
    float s0 = 0.f, s1 = 0.f;
#pragma unroll 8
    for (int s = 0; s < HB; ++s) {
        s0 += p0[(size_t)s * HBINS];
        s1 += p1[(size_t)s * HBINS];
    }
    c_src[n] = s0;
    c_dst[n] = s1;
}

// ---------------- K2: column-sum of edge_attr (E,6) ----------------
__global__ __launch_bounds__(256) void k_edgesum(const float* __restrict__ ea,
                                                 float* __restrict__ sum_attr, int E) {
    int nchunk = E >> 1;
    float a0 = 0, a1 = 0, a2 = 0, a3 = 0, a4 = 0, a5 = 0;
    for (int c = blockIdx.x * blockDim.x + threadIdx.x; c < nchunk;
         c += gridDim.x * blockDim.x) {
        const float4* p = (const float4*)(ea + (size_t)c * 12);
        float4 v0 = p[0], v1 = p[1], v2 = p[2];
        a0 += v0.x + v1.z;  a1 += v0.y + v1.w;  a2 += v0.z + v2.x;
        a3 += v0.w + v2.y;  a4 += v1.x + v2.z;  a5 += v1.y + v2.w;
    }
#pragma unroll
    for (int m = 32; m; m >>= 1) {
        a0 += __shfl_xor(a0, m); a1 += __shfl_xor(a1, m); a2 += __shfl_xor(a2, m);
        a3 += __shfl_xor(a3, m); a4 += __shfl_xor(a4, m); a5 += __shfl_xor(a5, m);
    }
    __shared__ float sbuf[4][6];
    int lane = threadIdx.x & 63, w = threadIdx.x >> 6;
    if (lane == 0) {
        sbuf[w][0] = a0; sbuf[w][1] = a1; sbuf[w][2] = a2;
        sbuf[w][3] = a3; sbuf[w][4] = a4; sbuf[w][5] = a5;
    }
    __syncthreads();
    if (threadIdx.x < 6) {
        float s = sbuf[0][threadIdx.x] + sbuf[1][threadIdx.x] +
                  sbuf[2][threadIdx.x] + sbuf[3][threadIdx.x];
        atomicAdd(&sum_attr[threadIdx.x], s);
    }
    if (blockIdx.x == 0 && threadIdx.x < 6 && (E & 1))
        atomicAdd(&sum_attr[threadIdx.x], ea[(size_t)(E - 1) * 6 + threadIdx.x]);
}

// ---------------- K3: weighted column sums of x -> per-block partials ----------------
__global__ __launch_bounds__(256) void k_xsum(const float* __restrict__ x,
        const float* __restrict__ c_src, const float* __restrict__ c_dst,
        float* __restrict__ xpart, int N) {
    int lane = threadIdx.x & 63, w = threadIdx.x >> 6;
    int wid = blockIdx.x * 4 + w, nw = gridDim.x * 4;
    float as0 = 0, ad0 = 0, as1 = 0, ad1 = 0;
    int Q = N >> 2;
    for (int q = wid; q < Q; q += nw) {
        int n = q * 4;
        const float* xr = x + (size_t)n * XDIM;
        float x0 = xr[lane];
        float x1 = xr[XDIM + lane];
        float x2 = xr[2 * XDIM + lane];
        float x3 = xr[3 * XDIM + lane];
        float4 cs = *(const float4*)(c_src + n);
        float4 cd = *(const float4*)(c_dst + n);
        as0 = fmaf(cs.x, x0, as0); as0 = fmaf(cs.y, x1, as0);
        as0 = fmaf(cs.z, x2, as0); as0 = fmaf(cs.w, x3, as0);
        ad0 = fmaf(cd.x, x0, ad0); ad0 = fmaf(cd.y, x1, ad0);
        ad0 = fmaf(cd.z, x2, ad0); ad0 = fmaf(cd.w, x3, ad0);
        if (lane < 2) {
            float e0 = xr[64 + lane];
            float e1 = xr[XDIM + 64 + lane];
            float e2 = xr[2 * XDIM + 64 + lane];
            float e3 = xr[3 * XDIM + 64 + lane];
            as1 = fmaf(cs.x, e0, as1); as1 = fmaf(cs.y, e1, as1);
            as1 = fmaf(cs.z, e2, as1); as1 = fmaf(cs.w, e3, as1);
            ad1 = fmaf(cd.x, e0, ad1); ad1 = fmaf(cd.y, e1, ad1);
            ad1 = fmaf(cd.z, e2, ad1); ad1 = fmaf(cd.w, e3, ad1);
        }
    }
    if (wid == 0) {
        for (int n = Q * 4; n < N; ++n) {
            const float* xr = x + (size_t)n * XDIM;
            float cs = c_src[n], cd = c_dst[n];
            float xv = xr[lane];
            as0 = fmaf(cs, xv, as0);
            ad0 = fmaf(cd, xv, ad0);
            if (lane < 2) {
                float xe = xr[64 + lane];
                as1 = fmaf(cs, xe, as1);
                ad1 = fmaf(cd, xe, ad1);
            }
        }
    }
    __shared__ float redS[4][XDIM], redD[4][XDIM];
    redS[w][lane] = as0;  redD[w][lane] = ad0;
    if (lane < 2) { redS[w][64 + lane] = as1;  redD[w][64 + lane] = ad1; }
    __syncthreads();
    int t = threadIdx.x;
    float* xp = xpart + (size_t)blockIdx.x * 136;
    if (t < XDIM) {
        xp[t]        = redS[0][t] + redS[1][t] + redS[2][t] + redS[3][t];
        xp[XDIM + t] = redD[0][t] + redD[1][t] + redD[2][t] + redD[3][t];
    }
}

// ---------------- K3b: reduce xpart rows -> xs[132] ----------------
__global__ __launch_bounds__(64) void k_xred(const float* __restrict__ xpart,
                                             float* __restrict__ xs, int nb) {
    int e = blockIdx.x;
    int lane = threadIdx.x;
    float s = 0.f;
    for (int b = lane; b < nb; b += 64)
        s += xpart[(size_t)b * 136 + e];
#pragma unroll
    for (int m = 32; m; m >>= 1) s += __shfl_xor(s, m);
    if (lane == 0) xs[e] = s;
}

// ---------------- K6: mean_msg = ([s_src,s_dst,se] @ W)/E + mp_b ----------------
template <int FIRST>
__global__ __launch_bounds__(256) void k_mm(const float* __restrict__ sv,
        const float* __restrict__ sum_attr, const float* __restrict__ w_edge,
        const float* __restrict__ b_edge, const float* __restrict__ W,
        const float* __restrict__ mpb, float* __restrict__ mean_msg, float Ef,
        const float* __restrict__ w_node, const float* __restrict__ b_node) {
    __shared__ float sc[384];
    __shared__ float mred[256];
    int t = threadIdx.x;
    if (t < 128) {
        float ssrc, sdst;
        if (FIRST) {
            ssrc = Ef * b_node[t];
            sdst = ssrc;
#pragma unroll
            for (int k = 0; k < XDIM; ++k) {
                float wv = w_node[k * HDIM + t];
                ssrc = fmaf(sv[k], wv, ssrc);
                sdst = fmaf(sv[XDIM + k], wv, sdst);
            }
        } else {
            ssrc = sv[t] + sv[t + 128];
            sdst = sv[256 + t] + sv[384 + t];
        }
        sc[t] = ssrc;
        sc[128 + t] = sdst;
        float se = Ef * b_edge[t];
#pragma unroll
        for (int k = 0; k < EDIM; ++k) se = fmaf(sum_attr[k], w_edge[k * HDIM + t], se);
        sc[256 + t] = se;
    }
    __syncthreads();
    int col = blockIdx.x * 16 + (t & 15);
    int rg = t >> 4;
    float acc = 0.f;
#pragma unroll 4
    for (int r = rg * 24; r < rg * 24 + 24; ++r)
        acc = fmaf(sc[r], W[r * HDIM + col], acc);
    mred[t] = acc;
    __syncthreads();
    if (t < 16) {
        float s = 0.f;
#pragma unroll
        for (int g = 0; g < 16; ++g) s += mred[g * 16 + t];
        mean_msg[blockIdx.x * 16 + t] = s / Ef + mpb[blockIdx.x * 16 + t];
    }
}

// ---------------- K5: reduce per-block partials -> sbuf[512] ----------------
__global__ __launch_bounds__(256) void k_red(const float* __restrict__ partials,
                                             float* __restrict__ sbuf, int nb) {
    int b0 = blockIdx.x * 32;
    int b1 = min(nb, b0 + 32);
    int t = threadIdx.x;
    float s0 = 0.f, s1 = 0.f;
    for (int b = b0; b < b1; ++b) {
        const float* row = partials + (size_t)b * 512;
        s0 += row[t];
        s1 += row[t + 256];
    }
    atomicAdd(&sbuf[t], s0);
    atomicAdd(&sbuf[t + 256], s1);
}

// ---------------- K7: fused layer-0 via bf16 MFMA + LN epilogue ----------------
// 256 thr = 4 waves; block tile 64 rows x 128 cols; wave w: rows w*16..+16.
__global__ __launch_bounds__(256) void k_upd0(
        const float* __restrict__ x, const unsigned short* __restrict__ wtg,
        const float* __restrict__ b_node, const float* __restrict__ mean_msg,
        const float* __restrict__ ln_g, const float* __restrict__ ln_b,
        const float* __restrict__ c_src, const float* __restrict__ c_dst,
        float* __restrict__ h, float* __restrict__ partials, int N) {
    __shared__ unsigned short xl[64 * KP];    // 13312 B, row stride 208B (2-way max)
    __shared__ unsigned short wt[128 * KP];   // 26624 B, col-major W^T
    int t = threadIdx.x;
    int lane = t & 63, w = t >> 6;
    // stage W^T (linear copy of precomputed bf16)
    {
        const uint4* srcp = (const uint4*)wtg;
        uint4* dstp = (uint4*)wt;
        for (int i = t; i < 128 * KP / 8; i += 256) dstp[i] = srcp[i];
    }
    // zero x tile (covers pad cols + pad rows)
    for (int i = t; i < 64 * KP / 2; i += 256) ((unsigned*)xl)[i] = 0u;
    __syncthreads();
    int rowbase = blockIdx.x * 64;
    const float* xg = x + (size_t)rowbase * XDIM;
    int lim = min(64, N - rowbase) * XDIM;
    for (int i = t; i < 64 * XDIM; i += 256) {
        if (i < lim) {
            int r = i / XDIM, k = i - r * XDIM;
            xl[r * KP + k] = f2bf(xg[i]);
        }
    }
    int cl = lane & 15, g = lane >> 4;
    // per-lane column params for the 8 col-tiles
    float bm[8], gg[8], lb[8];
#pragma unroll
    for (int ct = 0; ct < 8; ++ct) {
        int col = ct * 16 + cl;
        bm[ct] = b_node[col] + mean_msg[col];
        gg[ct] = ln_g[col];
        lb[ct] = ln_b[col];
    }
    __syncthreads();

    fv4 acc[8];
#pragma unroll
    for (int ct = 0; ct < 8; ++ct) acc[ct] = (fv4){0.f, 0.f, 0.f, 0.f};
#pragma unroll
    for (int ks = 0; ks < 3; ++ks) {
        sv8 a = *(const sv8*)&xl[(w * 16 + cl) * KP + ks * 32 + g * 8];
#pragma unroll
        for (int ct = 0; ct < 8; ++ct) {
            sv8 b = *(const sv8*)&wt[(ct * 16 + cl) * KP + ks * 32 + g * 8];
            acc[ct] = __builtin_amdgcn_mfma_f32_16x16x32_bf16(a, b, acc[ct], 0, 0, 0);
        }
    }
    // D layout: row = (lane>>4)*4 + e (within wave's 16 rows), col = ct*16 + (lane&15)
    float v[8][4];
    float s[4] = {0.f, 0.f, 0.f, 0.f};
#pragma unroll
    for (int ct = 0; ct < 8; ++ct)
#pragma unroll
        for (int e = 0; e < 4; ++e) {
            v[ct][e] = acc[ct][e] + bm[ct];
            s[e] += v[ct][e];
        }
#pragma unroll
    for (int m = 1; m < 16; m <<= 1) {
        s[0] += __shfl_xor(s[0], m); s[1] += __shfl_xor(s[1], m);
        s[2] += __shfl_xor(s[2], m); s[3] += __shfl_xor(s[3], m);
    }
    float mu[4], q[4] = {0.f, 0.f, 0.f, 0.f};
#pragma unroll
    for (int e = 0; e < 4; ++e) mu[e] = s[e] * (1.0f / HDIM);
#pragma unroll
    for (int ct = 0; ct < 8; ++ct)
#pragma unroll
        for (int e = 0; e < 4; ++e) {
            float d = v[ct][e] - mu[e];
            q[e] = fmaf(d, d, q[e]);
        }
#pragma unroll
    for (int m = 1; m < 16; m <<= 1) {
        q[0] += __shfl_xor(q[0], m); q[1] += __shfl_xor(q[1], m);
        q[2] += __shfl_xor(q[2], m); q[3] += __shfl_xor(q[3], m);
    }
    float rs[4];
#pragma unroll
    for (int e = 0; e < 4; ++e) rs[e] = rsqrtf(q[e] * (1.0f / HDIM) + LN_EPS);

    int grow = rowbase + w * 16 + g * 4;
    float4 csv = *(const float4*)(c_src + grow);   // padded arrays, zero past N
    float4 cdv = *(const float4*)(c_dst + grow);
    float cs[4] = {csv.x, csv.y, csv.z, csv.w};
    float cd[4] = {cdv.x, cdv.y, cdv.z, cdv.w};
    float accS[8], accD[8];
#pragma unroll
    for (int ct = 0; ct < 8; ++ct) { accS[ct] = 0.f; accD[ct] = 0.f; }
#pragma unroll
    for (int e = 0; e < 4; ++e) {
        int row = grow + e;
        bool ok = (row < N);
#pragma unroll
        for (int ct = 0; ct < 8; ++ct) {
            float o = fmaxf(0.f, fmaf((v[ct][e] - mu[e]) * rs[e], gg[ct], lb[ct]));
            if (ok) h[(size_t)row * HDIM + ct * 16 + cl] = o;
            accS[ct] = fmaf(cs[e], o, accS[ct]);
            accD[ct] = fmaf(cd[e], o, accD[ct]);
        }
    }
#pragma unroll
    for (int ct = 0; ct < 8; ++ct) {
        accS[ct] += __shfl_xor(accS[ct], 16); accS[ct] += __shfl_xor(accS[ct], 32);
        accD[ct] += __shfl_xor(accD[ct], 16); accD[ct] += __shfl_xor(accD[ct], 32);
    }
    __syncthreads();   // xl no longer read by any wave
    float* redS = (float*)xl;          // [4][128]
    float* redD = redS + 512;
    if (g == 0) {
#pragma unroll
        for (int ct = 0; ct < 8; ++ct) {
            redS[w * HDIM + ct * 16 + cl] = accS[ct];
            redD[w * HDIM + ct * 16 + cl] = accD[ct];
        }
    }
    __syncthreads();
    if (t < 128) {
        float ss = redS[t] + redS[128 + t] + redS[256 + t] + redS[384 + t];
        float dd = redD[t] + redD[128 + t] + redD[256 + t] + redD[384 + t];
        float* row = partials + (size_t)blockIdx.x * 512;
        row[t] = ss;       row[t + 128] = 0.f;
        row[t + 256] = dd; row[t + 384] = 0.f;
    }
}

// ---------------- LN helper ----------------
__device__ __forceinline__ float2 ln_relu2(float2 v, float2 g, float2 bb) {
    float s = v.x + v.y;
#pragma unroll
    for (int m = 32; m; m >>= 1) s += __shfl_xor(s, m);
    float mu = s * (1.0f / HDIM);
    float dx = v.x - mu, dy = v.y - mu;
    float q = dx * dx + dy * dy;
#pragma unroll
    for (int m = 32; m; m >>= 1) q += __shfl_xor(q, m);
    float rs = rsqrtf(q * (1.0f / HDIM) + LN_EPS);
    float2 o;
    o.x = fmaxf(0.f, fmaf(dx * rs, g.x, bb.x));
    o.y = fmaxf(0.f, fmaf(dy * rs, g.y, bb.y));
    return o;
}

// ---------------- K8: h = relu(LN(h + mm)); next-layer sums or pooling ----------------
template <int LAST>
__global__ __launch_bounds__(256) void k_update(
        float* __restrict__ h, const float* __restrict__ mean_msg,
        const float* __restrict__ ln_g, const float* __restrict__ ln_b,
        const float* __restrict__ c_src, const float* __restrict__ c_dst,
        const int* __restrict__ batch, float* __restrict__ partials,
        float* __restrict__ pooled, int N, int cpb) {
    int t = threadIdx.x;
    int lane = t & 63, w = t >> 6;
    int c0 = lane * 2;
    float2 mm = *(const float2*)(mean_msg + c0);
    float2 g  = *(const float2*)(ln_g + c0);
    float2 bb = *(const float2*)(ln_b + c0);
    int start = blockIdx.x * cpb;
    int end = min(N, start + cpb);
    int spw = (cpb + 3) >> 2;
    int ns = start + w * spw;
    int ne = min(end, ns + spw);
    float2 accS = {0.f, 0.f}, accD = {0.f, 0.f}, accP = {0.f, 0.f};
    int cur_g = -1;
    int n = ns;
    for (; n + 4 <= ne; n += 4) {
        float2 v0 = *(const float2*)(h + (size_t)(n    ) * HDIM + c0);
        float2 v1 = *(const float2*)(h + (size_t)(n + 1) * HDIM + c0);
        float2 v2 = *(const float2*)(h + (size_t)(n + 2) * HDIM + c0);
        float2 v3 = *(const float2*)(h + (size_t)(n + 3) * HDIM + c0);
        v0.x += mm.x; v0.y += mm.y;  v1.x += mm.x; v1.y += mm.y;
        v2.x += mm.x; v2.y += mm.y;  v3.x += mm.x; v3.y += mm.y;
        float2 o0 = ln_relu2(v0, g, bb);
        float2 o1 = ln_relu2(v1, g, bb);
        float2 o2 = ln_relu2(v2, g, bb);
        float2 o3 = ln_relu2(v3, g, bb);
        if (LAST) {
            int gi[4] = {batch[n], batch[n + 1], batch[n + 2], batch[n + 3]};
            float2 oo[4] = {o0, o1, o2, o3};
#pragma unroll
            for (int r = 0; r < 4; ++r) {
                if (gi[r] != cur_g) {
                    if (cur_g >= 0) {
                        atomicAdd(&pooled[cur_g * HDIM + c0],     accP.x);
                        atomicAdd(&pooled[cur_g * HDIM + c0 + 1], accP.y);
                    }
                    accP.x = 0.f; accP.y = 0.f;
                    cur_g = gi[r];
                }
                accP.x += oo[r].x; accP.y += oo[r].y;
            }
        } else {
            *(float2*)(h + (size_t)(n    ) * HDIM + c0) = o0;
            *(float2*)(h + (size_t)(n + 1) * HDIM + c0) = o1;
            *(float2*)(h + (size_t)(n + 2) * HDIM + c0) = o2;
            *(float2*)(h + (size_t)(n + 3) * HDIM + c0) = o3;
            float cs0 = c_src[n], cs1 = c_src[n+1], cs2 = c_src[n+2], cs3 = c_src[n+3];
            float cd0 = c_dst[n], cd1 = c_dst[n+1], cd2 = c_dst[n+2], cd3 = c_dst[n+3];
            accS.x = fmaf(cs0, o0.x, accS.x); accS.y = fmaf(cs0, o0.y, accS.y);
            accS.x = fmaf(cs1, o1.x, accS.x); accS.y = fmaf(cs1, o1.y, accS.y);
            accS.x = fmaf(cs2, o2.x, accS.x); accS.y = fmaf(cs2, o2.y, accS.y);
            accS.x = fmaf(cs3, o3.x, accS.x); accS.y = fmaf(cs3, o3.y, accS.y);
            accD.x = fmaf(cd0, o0.x, accD.x); accD.y = fmaf(cd0, o0.y, accD.y);
            accD.x = fmaf(cd1, o1.x, accD.x); accD.y = fmaf(cd1, o1.y, accD.y);
            accD.x = fmaf(cd2, o2.x, accD.x); accD.y = fmaf(cd2, o2.y, accD.y);
            accD.x = fmaf(cd3, o3.x, accD.x); accD.y = fmaf(cd3, o3.y, accD.y);
        }
    }
    for (; n < ne; ++n) {
        float2 v = *(const float2*)(h + (size_t)n * HDIM + c0);
        v.x += mm.x; v.y += mm.y;
        float2 o = ln_relu2(v, g, bb);
        if (LAST) {
            int gg = batch[n];
            if (gg != cur_g) {
                if (cur_g >= 0) {
                    atomicAdd(&pooled[cur_g * HDIM + c0],     accP.x);
                    atomicAdd(&pooled[cur_g * HDIM + c0 + 1], accP.y);
                }
                accP.x = 0.f; accP.y = 0.f;
                cur_g = gg;
            }
            accP.x += o.x; accP.y += o.y;
        } else {
            *(float2*)(h + (size_t)n * HDIM + c0) = o;
            float cs = c_src[n], cd = c_dst[n];
            accS.x = fmaf(cs, o.x, accS.x); accS.y = fmaf(cs, o.y, accS.y);
            accD.x = fmaf(cd, o.x, accD.x); accD.y = fmaf(cd, o.y, accD.y);
        }
    }
    if (LAST) {
        if (cur_g >= 0) {
            atomicAdd(&pooled[cur_g * HDIM + c0],     accP.x);
            atomicAdd(&pooled[cur_g * HDIM + c0 + 1], accP.y);
        }
    } else {
        __shared__ float sb[HDIM], db[HDIM];
        if (t < HDIM) { sb[t] = 0.f; db[t] = 0.f; }
        __syncthreads();
        atomicAdd(&sb[c0], accS.x); atomicAdd(&sb[c0 + 1], accS.y);
        atomicAdd(&db[c0], accD.x); atomicAdd(&db[c0 + 1], accD.y);
        __syncthreads();
        float* row = partials + (size_t)blockIdx.x * 512;
        if (t < 128) {
            row[t] = sb[t];        row[t + 128] = 0.f;
            row[t + 256] = db[t];  row[t + 384] = 0.f;
        }
    }
}

// ---------------- K9: out = (pooled / max(cnt,1)) @ w_out + b_out ----------------
__global__ __launch_bounds__(128) void k_out(const float* __restrict__ pooled,
        const int* __restrict__ batch, const float* __restrict__ w_out,
        const float* __restrict__ b_out, float* __restrict__ out, int N) {
    int gph = blockIdx.x;
    int t = threadIdx.x;
    __shared__ float p[HDIM];
    __shared__ int cntS;
    if (t == 0) {
        int lo = 0, hi = N;
        while (lo < hi) { int mid = (lo + hi) >> 1; if (batch[mid] < gph) lo = mid + 1; else hi = mid; }
        int lo2 = lo, hi2 = N;
        while (lo2 < hi2) { int mid = (lo2 + hi2) >> 1; if (batch[mid] <= gph) lo2 = mid + 1; else hi2 = mid; }
        cntS = lo2 - lo;
    }
    __syncthreads();
    float inv = 1.0f / fmaxf((float)cntS, 1.0f);
    p[t] = pooled[gph * HDIM + t] * inv;
    __syncthreads();
    float acc = b_out[t];
#pragma unroll 8
    for (int k = 0; k < HDIM; ++k) acc = fmaf(p[k], w_out[k * HDIM + t], acc);
    out[gph * HDIM + t] = acc;
}

extern "C" void kernel_launch(void* const* d_in, const int* in_sizes, int n_in,
                              void* d_out, int out_size, void* d_ws, size_t ws_size,
                              hipStream_t stream) {
    const float* x      = (const float*)d_in[0];
    const int*   ei     = (const int*)d_in[1];
    const float* ea     = (const float*)d_in[2];
    const int*   batch  = (const int*)d_in[3];
    const float* w_node = (const float*)d_in[4];
    const float* b_node = (const float*)d_in[5];
    const float* w_edge = (const float*)d_in[6];
    const float* b_edge = (const float*)d_in[7];
    const float* mp_w   = (const float*)d_in[8];
    const float* mp_b   = (const float*)d_in[9];
    const float* ln_g   = (const float*)d_in[10];
    const float* ln_b   = (const float*)d_in[11];
    const float* w_out  = (const float*)d_in[12];
    const float* b_out  = (const float*)d_in[13];
    float* out = (float*)d_out;
    int N = in_sizes[3];
    int E = in_sizes[2] / EDIM;
    float Ef = (float)E;
    int ntiles0 = (N + 63) / 64;

    float* ws = (float*)d_ws;
    size_t off = 0;
    float* h        = ws + off; off += (size_t)N * HDIM;       // hist partials overlay here
    float* hist_part = h;   // 2*HR*HB*HBINS*4B = 13.1MB <= 51.2MB
    float* partials = ws + off; off += (size_t)2048 * 512;
    float* mean_msg = ws + off; off += 128;
    float* c_src    = ws + off; off += CBINS;
    float* c_dst    = ws + off; off += CBINS;
    float* xpart    = ws + off; off += (size_t)NBX * 136;
    unsigned short* wtg = (unsigned short*)(ws + off); off += 128 * KP / 2;  // bf16 W^T
    float* xs       = ws + off; off += 136;
    // ---- accumulator region (contiguous, zeroed every call) ----
    off = (off + 3) & ~(size_t)3;
    float* acc0     = ws + off;
    float* sum_attr = ws + off; off += 8;
    float* sbuf1    = ws + off; off += 512;
    float* sbuf2    = ws + off; off += 512;
    float* pooled   = ws + off; off += NGRAPHS * HDIM;
    size_t zero_count = (size_t)(ws + off - acc0);
    hipMemsetAsync(acc0, 0, zero_count * sizeof(float), stream);

    k_prep<<<1, 128, 0, stream>>>(w_node, wtg);
    k_hist_part<<<2 * HR * HB, 256, 0, stream>>>(ei, hist_part, E);
    k_hist_red<<<(CBINS + 255) / 256, 256, 0, stream>>>(hist_part, c_src, c_dst);
    k_edgesum<<<128, 256, 0, stream>>>(ea, sum_attr, E);
    k_xsum<<<NBX, 256, 0, stream>>>(x, c_src, c_dst, xpart, N);
    k_xred<<<2 * XDIM, 64, 0, stream>>>(xpart, xs, NBX);

    const int NB = 1024;
    int cpb = (N + NB - 1) / NB;

    // layer 0
    k_mm<1><<<8, 256, 0, stream>>>(xs, sum_attr, w_edge, b_edge,
                                   mp_w, mp_b, mean_msg, Ef, w_node, b_node);
    k_upd0<<<ntiles0, 256, 0, stream>>>(x, wtg, b_node, mean_msg, ln_g, ln_b,
                                        c_src, c_dst, h, partials, N);
    // layer 1
    k_red<<<(ntiles0 + 31) / 32, 256, 0, stream>>>(partials, sbuf1, ntiles0);
    k_mm<0><<<8, 256, 0, stream>>>(sbuf1, sum_attr, w_edge, b_edge,
                                   mp_w + (size_t)1 * 384 * HDIM,
                                   mp_b + (size_t)1 * HDIM, mean_msg, Ef,
                                   w_node, b_node);
    k_update<0><<<NB, 256, 0, stream>>>(h, mean_msg, ln_g, ln_b, c_src, c_dst,
                                        batch, partials, pooled, N, cpb);
    // layer 2
    k_red<<<NB / 32, 256, 0, stream>>>(partials, sbuf2, NB);
    k_mm<0><<<8, 256, 0, stream>>>(sbuf2, sum_attr, w_edge, b_edge,
                                   mp_w + (size_t)2 * 384 * HDIM,
                                   mp_b + (size_t)2 * HDIM, mean_msg, Ef,
                                   w_node, b_node);
    k_update<1><<<NB, 256, 0, stream>>>(h, mean_msg, ln_g, ln_b, c_src, c_dst,
                                        batch, partials, pooled, N, cpb);

    k_out<<<NGRAPHS, HDIM, 0, stream>>>(pooled, batch, w_out, b_out, out, N);
}